// Round 1
// 2567.933 us; speedup vs baseline: 2.0543x; 2.0543x over previous
//
#include <hip/hip_runtime.h>
#include <hip/hip_fp16.h>

// Problem dims (fixed by reference)
#define NB 512   // batch
#define NTT 256  // timesteps
#define ND 512   // input dim
#define NH 1024  // hidden dim
#define NK 1536  // ND + NH fused K

typedef _Float16 f16;
typedef f16 f16x8 __attribute__((ext_vector_type(8)));
typedef f16 f16x4 __attribute__((ext_vector_type(4)));
typedef float f32x4 __attribute__((ext_vector_type(4)));

union U16x8 { unsigned long long q[2]; f16x8 v; uint4 u4; };

// ws layout
#define BAR_BYTES 4096
#define WUT_OFF  BAR_BYTES
#define WUT_BYTES (NH * NK * 2)          // 3 MB: WUT[n][k] = k<512 ? W[k][n] : U[k-512][n]
#define H_OFF    (WUT_OFF + WUT_BYTES)
#define H_BYTES  (2 * NB * NH * 2)       // 2 MB ping-pong h

// ---------------------------------------------------------------------------
// Prep: WUT = [W;U]^T in fp16. grid = 24 (k-tiles) x 16 (n-tiles) = 384 blocks.
// ---------------------------------------------------------------------------
__global__ void prep_wut(const float* __restrict__ W, const float* __restrict__ U,
                         f16* __restrict__ WUT) {
    __shared__ float tile[64][65];
    int bk = blockIdx.x % 24, bn = blockIdx.x / 24;
    int k0 = bk * 64, n0 = bn * 64;
    int tid = threadIdx.x, jn = tid & 63;
#pragma unroll
    for (int p = 0; p < 16; ++p) {
        int kr = p * 4 + (tid >> 6);
        int k = k0 + kr;
        float v = (k < ND) ? W[(size_t)k * NH + n0 + jn] : U[(size_t)(k - ND) * NH + n0 + jn];
        tile[kr][jn] = v;
    }
    __syncthreads();
#pragma unroll
    for (int p = 0; p < 16; ++p) {
        int nr = p * 4 + (tid >> 6);
        int kc = tid & 63;
        WUT[(size_t)(n0 + nr) * NK + k0 + kc] = (f16)tile[kc][nr];
    }
}

__device__ __forceinline__ float fast_tanh(float x) {
    float e = __expf(-2.0f * x);
    return 2.0f / (1.0f + e) - 1.0f;
}

// ---------------------------------------------------------------------------
// Persistent kernel: 256 blocks x 512 threads (8 waves).
// 16 independent clusters of 16 blocks (co-XCD heuristic via bid&7; correctness
// does not depend on placement — cross-block traffic is agent-scope atomics,
// which legalize to sc1 (L2-bypass, device-coherent) accesses on gfx950).
// Cluster owns 32 batch rows; block owns 64 cols, weights register-resident
// (fused K=1536: x-part prefetched from global, h-part exchanged per step).
// 8 waves split K 8-ways: wave w: x-k [w*64,+64), h-k [w*128,+128).
//
// Sync redesign this round: NO __threadfence (no per-step buffer_wbl2/inv),
// and the cluster barrier is a flag ARRAY (one slot per member block, plain
// sc1 stores — parallel arrivals) instead of a single fetch_add counter
// (16 serialized memory-side RMWs). __syncthreads before the flag store
// drains vmcnt(0) (compiler-emitted), giving h-stores-before-flag ordering;
// pollers observe the flag then pass a __syncthreads (compiler + HW memory
// barrier) before issuing next-step h loads.
// ---------------------------------------------------------------------------
__global__ void __launch_bounds__(512, 1)
rnn4(const float* __restrict__ x, const f16* __restrict__ WUT,
     const float* __restrict__ bias, const float* __restrict__ Wd,
     const float* __restrict__ bd, f16* __restrict__ h,
     unsigned* __restrict__ bar, float* __restrict__ out) {
    __shared__ float red[4][64][36];   // [buf][col][row+pad] f32, 36864 B
    __shared__ f16 trans[32][72];      // epilogue transpose, 4608 B

    const int bid = blockIdx.x, tid = threadIdx.x;
    const int lane = tid & 63, wid = tid >> 6;
    const int lrow = lane & 15, lq = lane >> 4;
    const int xcd = bid & 7, m8 = bid >> 3;
    const int cl = xcd * 2 + (m8 >> 4);     // 0..15
    const int mem = m8 & 15;                // 0..15
    const int r0 = cl * 32, c0 = mem * 64;
    const int kx0 = wid * 64;               // x k-slice base
    const int kh0 = wid * 128;              // h k-slice base (global k = 512+kh0)
    unsigned* cnt = bar + cl * 32;          // 128-B spaced cluster flag arrays

    // ---- weights: register-resident WUT slice [c0..c0+64) x wave k-slice ----
    f16x8 bw[4][6];   // [j][kt]: kt 0..1 x-part, 2..5 h-part. 96 VGPRs.
    float bias_r[4];
#pragma unroll
    for (int j = 0; j < 4; ++j) {
        const int col = c0 + j * 16 + lrow;
        bias_r[j] = bias[col];
        const f16* wp = WUT + (size_t)col * NK;
#pragma unroll
        for (int kt = 0; kt < 2; ++kt)
            bw[j][kt] = *(const f16x8*)(wp + kx0 + kt * 32 + lq * 8);
#pragma unroll
        for (int kt = 0; kt < 4; ++kt)
            bw[j][2 + kt] = *(const f16x8*)(wp + ND + kh0 + kt * 32 + lq * 8);
    }

    // ---- x prefetch for t=0 ----
    float4 xf[2][2][2];   // [m][kt][half]
    {
        const int t0 = 0;
#pragma unroll
        for (int m = 0; m < 2; ++m) {
            const float* xp = x + (size_t)(r0 + m * 16 + lrow) * (NTT * ND)
                                + (size_t)t0 * ND + kx0 + lq * 8;
#pragma unroll
            for (int kt = 0; kt < 2; ++kt) {
                xf[m][kt][0] = *(const float4*)(xp + kt * 32);
                xf[m][kt][1] = *(const float4*)(xp + kt * 32 + 4);
            }
        }
    }

    for (int t = 0; t < NTT; ++t) {
        const f16* hprev = h + (size_t)(t & 1) * (NB * NH);
        f16* hnew = h + (size_t)((t + 1) & 1) * (NB * NH);

        // convert prefetched x to fragments
        f16x8 ax[2][2];
#pragma unroll
        for (int m = 0; m < 2; ++m)
#pragma unroll
            for (int kt = 0; kt < 2; ++kt) {
                const float4 a = xf[m][kt][0], b = xf[m][kt][1];
                f16x8 v = {(f16)a.x, (f16)a.y, (f16)a.z, (f16)a.w,
                           (f16)b.x, (f16)b.y, (f16)b.z, (f16)b.w};
                ax[m][kt] = v;
            }

        f32x4 acc[2][4] = {};
        // x-part MFMAs
#pragma unroll
        for (int kt = 0; kt < 2; ++kt)
#pragma unroll
            for (int m = 0; m < 2; ++m)
#pragma unroll
                for (int j = 0; j < 4; ++j)
                    acc[m][j] = __builtin_amdgcn_mfma_f32_16x16x32_f16(ax[m][kt], bw[j][kt], acc[m][j], 0, 0, 0);

        // h-part: agent-scope atomic loads (cross-XCD safe), then MFMA
#pragma unroll
        for (int kt = 0; kt < 4; ++kt) {
            U16x8 a0, a1;
            const f16* p0 = hprev + (size_t)(r0 + lrow) * NH + kh0 + kt * 32 + lq * 8;
            const f16* p1 = p0 + (size_t)16 * NH;
            a0.q[0] = __hip_atomic_load((const unsigned long long*)p0, __ATOMIC_RELAXED, __HIP_MEMORY_SCOPE_AGENT);
            a0.q[1] = __hip_atomic_load((const unsigned long long*)p0 + 1, __ATOMIC_RELAXED, __HIP_MEMORY_SCOPE_AGENT);
            a1.q[0] = __hip_atomic_load((const unsigned long long*)p1, __ATOMIC_RELAXED, __HIP_MEMORY_SCOPE_AGENT);
            a1.q[1] = __hip_atomic_load((const unsigned long long*)p1 + 1, __ATOMIC_RELAXED, __HIP_MEMORY_SCOPE_AGENT);
#pragma unroll
            for (int j = 0; j < 4; ++j) {
                acc[0][j] = __builtin_amdgcn_mfma_f32_16x16x32_f16(a0.v, bw[j][2 + kt], acc[0][j], 0, 0, 0);
                acc[1][j] = __builtin_amdgcn_mfma_f32_16x16x32_f16(a1.v, bw[j][2 + kt], acc[1][j], 0, 0, 0);
            }
        }

        // ---- 8 -> 1 split-K tree reduction in LDS ----
#define ST_PARTIAL(B)                                                          \
        {                                                                      \
            _Pragma("unroll")                                                  \
            for (int m = 0; m < 2; ++m)                                        \
                _Pragma("unroll")                                              \
                for (int j = 0; j < 4; ++j)                                    \
                    *(f32x4*)&red[B][j * 16 + lrow][m * 16 + lq * 4] = acc[m][j]; \
        }
#define ADD_PARTIAL(B)                                                         \
        {                                                                      \
            _Pragma("unroll")                                                  \
            for (int m = 0; m < 2; ++m)                                        \
                _Pragma("unroll")                                              \
                for (int j = 0; j < 4; ++j)                                    \
                    acc[m][j] += *(const f32x4*)&red[B][j * 16 + lrow][m * 16 + lq * 4]; \
        }
        if (wid >= 4) ST_PARTIAL(wid - 4);
        __syncthreads();
        if (wid < 4) ADD_PARTIAL(wid);
        __syncthreads();
        if (wid == 2 || wid == 3) ST_PARTIAL(wid - 2);
        __syncthreads();
        if (wid < 2) ADD_PARTIAL(wid);
        __syncthreads();
        if (wid == 1) ST_PARTIAL(0);
        __syncthreads();

        // ---- epilogue (wave 0): bias + tanh, transpose, store h_new ----
        if (wid == 0) {
            ADD_PARTIAL(0);
#pragma unroll
            for (int m = 0; m < 2; ++m)
#pragma unroll
                for (int j = 0; j < 4; ++j) {
                    const int c = j * 16 + lrow, rb = m * 16 + lq * 4;
#pragma unroll
                    for (int r = 0; r < 4; ++r)
                        trans[rb + r][c] = (f16)fast_tanh(acc[m][j][r] + bias_r[j]);
                }
            // wave-local LDS write->read (compiler inserts lgkmcnt)
            const int rr = lane >> 1, ch = (lane & 1) * 32;
            f16* dst = hnew + (size_t)(r0 + rr) * NH + c0 + ch;
#pragma unroll
            for (int s = 0; s < 4; ++s) {
                U16x8 u; u.v = *(const f16x8*)&trans[rr][ch + s * 8];
                __hip_atomic_store((unsigned long long*)(dst + s * 8), u.q[0], __ATOMIC_RELAXED, __HIP_MEMORY_SCOPE_AGENT);
                __hip_atomic_store((unsigned long long*)(dst + s * 8) + 1, u.q[1], __ATOMIC_RELAXED, __HIP_MEMORY_SCOPE_AGENT);
            }
        }

        // ---- prefetch x for t+1 (latency hides under barrier) ----
        const int tn = (t + 1 < NTT) ? t + 1 : NTT - 1;
#pragma unroll
        for (int m = 0; m < 2; ++m) {
            const float* xp = x + (size_t)(r0 + m * 16 + lrow) * (NTT * ND)
                                + (size_t)tn * ND + kx0 + lq * 8;
#pragma unroll
            for (int kt = 0; kt < 2; ++kt) {
                xf[m][kt][0] = *(const float4*)(xp + kt * 32);
                xf[m][kt][1] = *(const float4*)(xp + kt * 32 + 4);
            }
        }

        // ---- cluster barrier: per-block flag slots, parallel arrivals/polls.
        // No fences: h traffic is sc1 (device-coherent); __syncthreads drains
        // vmcnt(0) so every wave's h stores are globally visible before the
        // flag store; pollers pass a __syncthreads before next-step h loads.
        __syncthreads();
        if (tid == 0)
            __hip_atomic_store(cnt + mem, (unsigned)(t + 1), __ATOMIC_RELAXED, __HIP_MEMORY_SCOPE_AGENT);
        if (tid < 16) {
            while (__hip_atomic_load(cnt + tid, __ATOMIC_RELAXED, __HIP_MEMORY_SCOPE_AGENT) < (unsigned)(t + 1))
                __builtin_amdgcn_s_sleep(1);
        }
        __syncthreads();
    }

    // ---- dense head: cluster leader computes out[r0..r0+32) ----
    if (mem == 0) {
        const f16* hlast = h;                   // parity 0 (NTT even)
        const int r = tid >> 4, seg = tid & 15; // 32 rows x 16 segments of 64
        const f16* hp = hlast + (size_t)(r0 + r) * NH + seg * 64;
        const float* wp = Wd + seg * 64;
        float s = 0.f;
#pragma unroll
        for (int i = 0; i < 64; i += 8) {
            U16x8 u;
            u.q[0] = __hip_atomic_load((const unsigned long long*)(hp + i), __ATOMIC_RELAXED, __HIP_MEMORY_SCOPE_AGENT);
            u.q[1] = __hip_atomic_load((const unsigned long long*)(hp + i) + 1, __ATOMIC_RELAXED, __HIP_MEMORY_SCOPE_AGENT);
            const float4 w0 = *(const float4*)(wp + i);
            const float4 w1 = *(const float4*)(wp + i + 4);
            s += (float)u.v[0] * w0.x + (float)u.v[1] * w0.y +
                 (float)u.v[2] * w0.z + (float)u.v[3] * w0.w +
                 (float)u.v[4] * w1.x + (float)u.v[5] * w1.y +
                 (float)u.v[6] * w1.z + (float)u.v[7] * w1.w;
        }
        s += __shfl_xor(s, 1); s += __shfl_xor(s, 2);
        s += __shfl_xor(s, 4); s += __shfl_xor(s, 8);
        if (seg == 0) out[r0 + r] = s + bd[0];
    }
}

// ---------------------------------------------------------------------------
extern "C" void kernel_launch(void* const* d_in, const int* in_sizes, int n_in,
                              void* d_out, int out_size, void* d_ws, size_t ws_size,
                              hipStream_t stream) {
    const float* x  = (const float*)d_in[0];
    const float* W  = (const float*)d_in[1];
    const float* U  = (const float*)d_in[2];
    const float* b  = (const float*)d_in[3];
    const float* Wd = (const float*)d_in[4];
    const float* bd = (const float*)d_in[5];
    float* out = (float*)d_out;

    char* ws = (char*)d_ws;
    unsigned* bar = (unsigned*)ws;
    f16* WUT = (f16*)(ws + WUT_OFF);
    f16* h   = (f16*)(ws + H_OFF);

    hipMemsetAsync(bar, 0, BAR_BYTES, stream);
    hipMemsetAsync(h, 0, NB * NH * 2, stream);   // h_0 = 0 (parity 0)
    prep_wut<<<dim3(384), dim3(256), 0, stream>>>(W, U, WUT);

    void* args[8] = {(void*)&x, (void*)&WUT, (void*)&b, (void*)&Wd,
                     (void*)&bd, (void*)&h, (void*)&bar, (void*)&out};
    hipError_t err = hipLaunchCooperativeKernel(
        reinterpret_cast<const void*>(&rnn4), dim3(256), dim3(512), args, 0, stream);
    if (err != hipSuccess) {
        // Plain-launch fallback: 256 blocks of 8 waves fit 1/CU on 256 CUs;
        // sync is our own cluster-local atomic barrier, not cg.
        rnn4<<<dim3(256), dim3(512), 0, stream>>>(x, WUT, b, Wd, bd, h, bar, out);
    }
}

// Round 2
// 2058.822 us; speedup vs baseline: 2.5623x; 1.2473x over previous
//
#include <hip/hip_runtime.h>
#include <hip/hip_fp16.h>

// Problem dims (fixed by reference)
#define NB 512   // batch
#define NTT 256  // timesteps
#define ND 512   // input dim
#define NH 1024  // hidden dim
#define NK 1536  // ND + NH fused K

typedef _Float16 f16;
typedef f16 f16x8 __attribute__((ext_vector_type(8)));
typedef f16 f16x4 __attribute__((ext_vector_type(4)));
typedef float f32x4 __attribute__((ext_vector_type(4)));

union U16x8 { unsigned long long q[2]; f16x8 v; uint4 u4; };
union U16x4 { unsigned long long q; f16x4 v; };

// ws layout
#define BAR_BYTES 4096
#define WUT_OFF  BAR_BYTES
#define WUT_BYTES (NH * NK * 2)          // 3 MB: WUT[n][k] = k<512 ? W[k][n] : U[k-512][n]
#define H_OFF    (WUT_OFF + WUT_BYTES)
#define H_BYTES  (2 * NB * NH * 2)       // 2 MB ping-pong h

// ---------------------------------------------------------------------------
// Prep: WUT = [W;U]^T in fp16. grid = 24 (k-tiles) x 16 (n-tiles) = 384 blocks.
// ---------------------------------------------------------------------------
__global__ void prep_wut(const float* __restrict__ W, const float* __restrict__ U,
                         f16* __restrict__ WUT) {
    __shared__ float tile[64][65];
    int bk = blockIdx.x % 24, bn = blockIdx.x / 24;
    int k0 = bk * 64, n0 = bn * 64;
    int tid = threadIdx.x, jn = tid & 63;
#pragma unroll
    for (int p = 0; p < 16; ++p) {
        int kr = p * 4 + (tid >> 6);
        int k = k0 + kr;
        float v = (k < ND) ? W[(size_t)k * NH + n0 + jn] : U[(size_t)(k - ND) * NH + n0 + jn];
        tile[kr][jn] = v;
    }
    __syncthreads();
#pragma unroll
    for (int p = 0; p < 16; ++p) {
        int nr = p * 4 + (tid >> 6);
        int kc = tid & 63;
        WUT[(size_t)(n0 + nr) * NK + k0 + kc] = (f16)tile[kc][nr];
    }
}

__device__ __forceinline__ float fast_tanh(float x) {
    float e = __expf(-2.0f * x);
    return 2.0f / (1.0f + e) - 1.0f;
}

// ---------------------------------------------------------------------------
// Persistent kernel: 256 blocks x 512 threads (8 waves).
// 16 clusters of 16 blocks; cluster owns 32 batch rows; block owns 64 cols,
// weights register-resident (fused K=1536). 8 waves split K 8-ways.
//
// This round: flattened reduction (8->4 in regs, 4-buf flat sum) and the
// epilogue (tanh + transpose + h stores) parallelized across ALL 8 waves.
// h_new stored as coalesced 8B-per-thread segments (full 64B line coverage;
// kills the 4x memory-side write amplification of partial-line sc1 stores).
// Syncthreads per step: 7 -> 5.
// ---------------------------------------------------------------------------
__global__ void __launch_bounds__(512, 1)
rnn4(const float* __restrict__ x, const f16* __restrict__ WUT,
     const float* __restrict__ bias, const float* __restrict__ Wd,
     const float* __restrict__ bd, f16* __restrict__ h,
     unsigned* __restrict__ bar, float* __restrict__ out) {
    __shared__ float red[4][64][36];   // [buf][col][row+pad] f32, 36864 B
    __shared__ f16 trans[32][72];      // epilogue transpose, 4608 B

    const int bid = blockIdx.x, tid = threadIdx.x;
    const int lane = tid & 63, wid = tid >> 6;
    const int lrow = lane & 15, lq = lane >> 4;
    const int xcd = bid & 7, m8 = bid >> 3;
    const int cl = xcd * 2 + (m8 >> 4);     // 0..15
    const int mem = m8 & 15;                // 0..15
    const int r0 = cl * 32, c0 = mem * 64;
    const int kx0 = wid * 64;               // x k-slice base
    const int kh0 = wid * 128;              // h k-slice base (global k = 512+kh0)
    unsigned* cnt = bar + cl * 32;          // 128-B spaced cluster flag arrays

    // epilogue ownership: wave handles cols [wid*8, wid*8+8) x all 32 rows
    const int ec = wid * 8 + (lane & 7);    // local col 0..63
    const int eq = lane >> 3;               // row quad 0..7
    const float bias_e = bias[c0 + ec];

    // readback/store ownership: thread stores 8B (4 cols) of one row
    const int srow = tid >> 4, sseg = tid & 15;

    // ---- weights: register-resident WUT slice [c0..c0+64) x wave k-slice ----
    f16x8 bw[4][6];   // [j][kt]: kt 0..1 x-part, 2..5 h-part. 96 VGPRs.
#pragma unroll
    for (int j = 0; j < 4; ++j) {
        const int col = c0 + j * 16 + lrow;
        const f16* wp = WUT + (size_t)col * NK;
#pragma unroll
        for (int kt = 0; kt < 2; ++kt)
            bw[j][kt] = *(const f16x8*)(wp + kx0 + kt * 32 + lq * 8);
#pragma unroll
        for (int kt = 0; kt < 4; ++kt)
            bw[j][2 + kt] = *(const f16x8*)(wp + ND + kh0 + kt * 32 + lq * 8);
    }

    // ---- x prefetch for t=0 ----
    float4 xf[2][2][2];   // [m][kt][half]
#pragma unroll
    for (int m = 0; m < 2; ++m) {
        const float* xp = x + (size_t)(r0 + m * 16 + lrow) * (NTT * ND)
                            + kx0 + lq * 8;
#pragma unroll
        for (int kt = 0; kt < 2; ++kt) {
            xf[m][kt][0] = *(const float4*)(xp + kt * 32);
            xf[m][kt][1] = *(const float4*)(xp + kt * 32 + 4);
        }
    }

    for (int t = 0; t < NTT; ++t) {
        const f16* hprev = h + (size_t)(t & 1) * (NB * NH);
        f16* hnew = h + (size_t)((t + 1) & 1) * (NB * NH);

        // convert prefetched x to fragments
        f16x8 ax[2][2];
#pragma unroll
        for (int m = 0; m < 2; ++m)
#pragma unroll
            for (int kt = 0; kt < 2; ++kt) {
                const float4 a = xf[m][kt][0], b = xf[m][kt][1];
                f16x8 v = {(f16)a.x, (f16)a.y, (f16)a.z, (f16)a.w,
                           (f16)b.x, (f16)b.y, (f16)b.z, (f16)b.w};
                ax[m][kt] = v;
            }

        f32x4 acc[2][4] = {};
        // x-part MFMAs
#pragma unroll
        for (int kt = 0; kt < 2; ++kt)
#pragma unroll
            for (int m = 0; m < 2; ++m)
#pragma unroll
                for (int j = 0; j < 4; ++j)
                    acc[m][j] = __builtin_amdgcn_mfma_f32_16x16x32_f16(ax[m][kt], bw[j][kt], acc[m][j], 0, 0, 0);

        // h-part: agent-scope atomic loads (cross-XCD safe), then MFMA
#pragma unroll
        for (int kt = 0; kt < 4; ++kt) {
            U16x8 a0, a1;
            const f16* p0 = hprev + (size_t)(r0 + lrow) * NH + kh0 + kt * 32 + lq * 8;
            const f16* p1 = p0 + (size_t)16 * NH;
            a0.q[0] = __hip_atomic_load((const unsigned long long*)p0, __ATOMIC_RELAXED, __HIP_MEMORY_SCOPE_AGENT);
            a0.q[1] = __hip_atomic_load((const unsigned long long*)p0 + 1, __ATOMIC_RELAXED, __HIP_MEMORY_SCOPE_AGENT);
            a1.q[0] = __hip_atomic_load((const unsigned long long*)p1, __ATOMIC_RELAXED, __HIP_MEMORY_SCOPE_AGENT);
            a1.q[1] = __hip_atomic_load((const unsigned long long*)p1 + 1, __ATOMIC_RELAXED, __HIP_MEMORY_SCOPE_AGENT);
#pragma unroll
            for (int j = 0; j < 4; ++j) {
                acc[0][j] = __builtin_amdgcn_mfma_f32_16x16x32_f16(a0.v, bw[j][2 + kt], acc[0][j], 0, 0, 0);
                acc[1][j] = __builtin_amdgcn_mfma_f32_16x16x32_f16(a1.v, bw[j][2 + kt], acc[1][j], 0, 0, 0);
            }
        }

        // ---- prefetch x for t+1 (issue early; latency hides under reduction) ----
        const int tn = (t + 1 < NTT) ? t + 1 : NTT - 1;
#pragma unroll
        for (int m = 0; m < 2; ++m) {
            const float* xp = x + (size_t)(r0 + m * 16 + lrow) * (NTT * ND)
                                + (size_t)tn * ND + kx0 + lq * 8;
#pragma unroll
            for (int kt = 0; kt < 2; ++kt) {
                xf[m][kt][0] = *(const float4*)(xp + kt * 32);
                xf[m][kt][1] = *(const float4*)(xp + kt * 32 + 4);
            }
        }

        // ---- split-K reduction: 8 -> 4 (regs) -> flat 4-buf sum ----
#define ST_PARTIAL(B)                                                          \
        {                                                                      \
            _Pragma("unroll")                                                  \
            for (int m = 0; m < 2; ++m)                                        \
                _Pragma("unroll")                                              \
                for (int j = 0; j < 4; ++j)                                    \
                    *(f32x4*)&red[B][j * 16 + lrow][m * 16 + lq * 4] = acc[m][j]; \
        }
#define ADD_PARTIAL(B)                                                         \
        {                                                                      \
            _Pragma("unroll")                                                  \
            for (int m = 0; m < 2; ++m)                                        \
                _Pragma("unroll")                                              \
                for (int j = 0; j < 4; ++j)                                    \
                    acc[m][j] += *(const f32x4*)&red[B][j * 16 + lrow][m * 16 + lq * 4]; \
        }
        if (wid >= 4) ST_PARTIAL(wid - 4);
        __syncthreads();
        if (wid < 4) {
            ADD_PARTIAL(wid);      // acc = own + partner partial (2-way sums)
            ST_PARTIAL(wid);       // same-wave RAW on own buf: program-order safe
        }
        __syncthreads();

        // ---- epilogue: ALL 8 waves. wave -> 8 cols x 32 rows ----
        {
            f32x4 s = *(const f32x4*)&red[0][ec][eq * 4];
#pragma unroll
            for (int b = 1; b < 4; ++b)
                s += *(const f32x4*)&red[b][ec][eq * 4];
#pragma unroll
            for (int r = 0; r < 4; ++r)
                trans[eq * 4 + r][ec] = (f16)fast_tanh(s[r] + bias_e);
        }
        __syncthreads();

        // ---- store h_new: 512 threads x 8B, coalesced (full 64B lines) ----
        {
            U16x4 u;
            u.v = *(const f16x4*)&trans[srow][sseg * 4];
            __hip_atomic_store((unsigned long long*)(hnew + (size_t)(r0 + srow) * NH + c0 + sseg * 4),
                               u.q, __ATOMIC_RELAXED, __HIP_MEMORY_SCOPE_AGENT);
        }

        // ---- cluster barrier: per-block flag slots, parallel arrivals/polls.
        // __syncthreads drains vmcnt(0) so every wave's h stores are globally
        // visible before the flag store.
        __syncthreads();
        if (tid == 0)
            __hip_atomic_store(cnt + mem, (unsigned)(t + 1), __ATOMIC_RELAXED, __HIP_MEMORY_SCOPE_AGENT);
        if (tid < 16) {
            while (__hip_atomic_load(cnt + tid, __ATOMIC_RELAXED, __HIP_MEMORY_SCOPE_AGENT) < (unsigned)(t + 1))
                __builtin_amdgcn_s_sleep(1);
        }
        __syncthreads();
    }

    // ---- dense head: cluster leader computes out[r0..r0+32) ----
    if (mem == 0) {
        const f16* hlast = h;                   // parity 0 (NTT even)
        const int r = tid >> 4, seg = tid & 15; // 32 rows x 16 segments of 64
        const f16* hp = hlast + (size_t)(r0 + r) * NH + seg * 64;
        const float* wp = Wd + seg * 64;
        float s = 0.f;
#pragma unroll
        for (int i = 0; i < 64; i += 8) {
            U16x8 u;
            u.q[0] = __hip_atomic_load((const unsigned long long*)(hp + i), __ATOMIC_RELAXED, __HIP_MEMORY_SCOPE_AGENT);
            u.q[1] = __hip_atomic_load((const unsigned long long*)(hp + i) + 1, __ATOMIC_RELAXED, __HIP_MEMORY_SCOPE_AGENT);
            const float4 w0 = *(const float4*)(wp + i);
            const float4 w1 = *(const float4*)(wp + i + 4);
            s += (float)u.v[0] * w0.x + (float)u.v[1] * w0.y +
                 (float)u.v[2] * w0.z + (float)u.v[3] * w0.w +
                 (float)u.v[4] * w1.x + (float)u.v[5] * w1.y +
                 (float)u.v[6] * w1.z + (float)u.v[7] * w1.w;
        }
        s += __shfl_xor(s, 1); s += __shfl_xor(s, 2);
        s += __shfl_xor(s, 4); s += __shfl_xor(s, 8);
        if (seg == 0) out[r0 + r] = s + bd[0];
    }
}

// ---------------------------------------------------------------------------
extern "C" void kernel_launch(void* const* d_in, const int* in_sizes, int n_in,
                              void* d_out, int out_size, void* d_ws, size_t ws_size,
                              hipStream_t stream) {
    const float* x  = (const float*)d_in[0];
    const float* W  = (const float*)d_in[1];
    const float* U  = (const float*)d_in[2];
    const float* b  = (const float*)d_in[3];
    const float* Wd = (const float*)d_in[4];
    const float* bd = (const float*)d_in[5];
    float* out = (float*)d_out;

    char* ws = (char*)d_ws;
    unsigned* bar = (unsigned*)ws;
    f16* WUT = (f16*)(ws + WUT_OFF);
    f16* h   = (f16*)(ws + H_OFF);

    hipMemsetAsync(bar, 0, BAR_BYTES, stream);
    hipMemsetAsync(h, 0, NB * NH * 2, stream);   // h_0 = 0 (parity 0)
    prep_wut<<<dim3(384), dim3(256), 0, stream>>>(W, U, WUT);

    void* args[8] = {(void*)&x, (void*)&WUT, (void*)&b, (void*)&Wd,
                     (void*)&bd, (void*)&h, (void*)&bar, (void*)&out};
    hipError_t err = hipLaunchCooperativeKernel(
        reinterpret_cast<const void*>(&rnn4), dim3(256), dim3(512), args, 0, stream);
    if (err != hipSuccess) {
        // Plain-launch fallback: 256 blocks of 8 waves fit 1/CU on 256 CUs;
        // sync is our own cluster-local atomic barrier, not cg.
        rnn4<<<dim3(256), dim3(512), 0, stream>>>(x, WUT, b, Wd, bd, h, bar, out);
    }
}

// Round 4
// 2007.458 us; speedup vs baseline: 2.6279x; 1.0256x over previous
//
#include <hip/hip_runtime.h>
#include <hip/hip_fp16.h>

// Problem dims (fixed by reference)
#define NB 512   // batch
#define NTT 256  // timesteps
#define ND 512   // input dim
#define NH 1024  // hidden dim
#define NK 1536  // ND + NH fused K

typedef _Float16 f16;
typedef f16 f16x8 __attribute__((ext_vector_type(8)));
typedef f16 f16x4 __attribute__((ext_vector_type(4)));
typedef float f32x4 __attribute__((ext_vector_type(4)));

union U16x8 { unsigned long long q[2]; f16x8 v; uint4 u4; };
union U16x4 { unsigned long long q; f16x4 v; };

// ws layout
#define BAR_BYTES 4096
#define WUT_OFF  BAR_BYTES
#define WUT_BYTES (NH * NK * 2)          // 3 MB: WUT[n][k] = k<512 ? W[k][n] : U[k-512][n]
#define H_OFF    (WUT_OFF + WUT_BYTES)
#define H_BYTES  (2 * NB * NH * 2)       // 2 MB ping-pong h

// ---------------------------------------------------------------------------
// Prep: WUT = [W;U]^T in fp16. grid = 24 (k-tiles) x 16 (n-tiles) = 384 blocks.
// ---------------------------------------------------------------------------
__global__ void prep_wut(const float* __restrict__ W, const float* __restrict__ U,
                         f16* __restrict__ WUT) {
    __shared__ float tile[64][65];
    int bk = blockIdx.x % 24, bn = blockIdx.x / 24;
    int k0 = bk * 64, n0 = bn * 64;
    int tid = threadIdx.x, jn = tid & 63;
#pragma unroll
    for (int p = 0; p < 16; ++p) {
        int kr = p * 4 + (tid >> 6);
        int k = k0 + kr;
        float v = (k < ND) ? W[(size_t)k * NH + n0 + jn] : U[(size_t)(k - ND) * NH + n0 + jn];
        tile[kr][jn] = v;
    }
    __syncthreads();
#pragma unroll
    for (int p = 0; p < 16; ++p) {
        int nr = p * 4 + (tid >> 6);
        int kc = tid & 63;
        WUT[(size_t)(n0 + nr) * NK + k0 + kc] = (f16)tile[kc][nr];
    }
}

__device__ __forceinline__ float fast_tanh(float x) {
    float e = __expf(-2.0f * x);
    return 2.0f / (1.0f + e) - 1.0f;
}

// ---------------------------------------------------------------------------
// Persistent kernel: 256 blocks x 512 threads (8 waves).
// 16 clusters of 16 blocks; cluster owns 32 batch rows; block owns 64 cols,
// weights register-resident (fused K=1536). 8 waves split K 8-ways.
//
// Sync protocol (per-wave producer flags):
//  - Wave wid consumes h cols [wid*128, +128) — produced by exactly blocks
//    mem = 2*wid, 2*wid+1. Each wave polls only those two flags, AFTER the
//    x-part MFMAs (h-independent), so the wait overlaps compute.
//  - Ping-pong safety: the reduction __syncthreads rejoins all 8 waves each
//    step, so a block reaches its step-t+1 stores only after its waves
//    collectively observed ALL 16 flags >= t+1 => every cluster block
//    finished reading h_t => overwriting parity t&1 is safe (skew <= 1).
//  - Dense head waits for all 16 flags == NTT before reading h_NTT.
//  - sched_barrier(0) after each poll loop pins the relaxed h loads below
//    the flag observation at compile time (HW issue is in-order).
// ---------------------------------------------------------------------------
__global__ void __launch_bounds__(512, 1)
rnn4(const float* __restrict__ x, const f16* __restrict__ WUT,
     const float* __restrict__ bias, const float* __restrict__ Wd,
     const float* __restrict__ bd, f16* __restrict__ h,
     unsigned* __restrict__ bar, float* __restrict__ out) {
    __shared__ float red[4][64][36];   // [buf][col][row+pad] f32, 36864 B
    __shared__ f16 trans[32][72];      // epilogue transpose, 4608 B

    const int bid = blockIdx.x, tid = threadIdx.x;
    const int lane = tid & 63, wid = tid >> 6;
    const int lrow = lane & 15, lq = lane >> 4;
    const int xcd = bid & 7, m8 = bid >> 3;
    const int cl = xcd * 2 + (m8 >> 4);     // 0..15
    const int mem = m8 & 15;                // 0..15
    const int r0 = cl * 32, c0 = mem * 64;
    const int kx0 = wid * 64;               // x k-slice base
    const int kh0 = wid * 128;              // h k-slice base (global k = 512+kh0)
    unsigned* cnt = bar + cl * 32;          // 128-B spaced cluster flag arrays

    // epilogue ownership: wave handles cols [wid*8, wid*8+8) x all 32 rows.
    // (b128 read of red is 8 lanes/4-bank slot — that's the wave64 b128
    // floor (1024B / 128B-per-clk), not a fixable conflict.)
    const int ec = wid * 8 + (lane & 7);    // local col 0..63
    const int eq = lane >> 3;               // row quad 0..7
    const float bias_e = bias[c0 + ec];

    // store ownership: thread stores 8B (4 cols) of one row
    const int srow = tid >> 4, sseg = tid & 15;

    // ---- weights: register-resident WUT slice [c0..c0+64) x wave k-slice ----
    f16x8 bw[4][6];   // [j][kt]: kt 0..1 x-part, 2..5 h-part. 96 VGPRs.
#pragma unroll
    for (int j = 0; j < 4; ++j) {
        const int col = c0 + j * 16 + lrow;
        const f16* wp = WUT + (size_t)col * NK;
#pragma unroll
        for (int kt = 0; kt < 2; ++kt)
            bw[j][kt] = *(const f16x8*)(wp + kx0 + kt * 32 + lq * 8);
#pragma unroll
        for (int kt = 0; kt < 4; ++kt)
            bw[j][2 + kt] = *(const f16x8*)(wp + ND + kh0 + kt * 32 + lq * 8);
    }

    // ---- x prefetch for t=0 ----
    float4 xf[2][2][2];   // [m][kt][half]
#pragma unroll
    for (int m = 0; m < 2; ++m) {
        const float* xp = x + (size_t)(r0 + m * 16 + lrow) * (NTT * ND)
                            + kx0 + lq * 8;
#pragma unroll
        for (int kt = 0; kt < 2; ++kt) {
            xf[m][kt][0] = *(const float4*)(xp + kt * 32);
            xf[m][kt][1] = *(const float4*)(xp + kt * 32 + 4);
        }
    }

    for (int t = 0; t < NTT; ++t) {
        const f16* hprev = h + (size_t)(t & 1) * (NB * NH);
        f16* hnew = h + (size_t)((t + 1) & 1) * (NB * NH);

        // convert prefetched x to fragments
        f16x8 ax[2][2];
#pragma unroll
        for (int m = 0; m < 2; ++m)
#pragma unroll
            for (int kt = 0; kt < 2; ++kt) {
                const float4 a = xf[m][kt][0], b = xf[m][kt][1];
                f16x8 v = {(f16)a.x, (f16)a.y, (f16)a.z, (f16)a.w,
                           (f16)b.x, (f16)b.y, (f16)b.z, (f16)b.w};
                ax[m][kt] = v;
            }

        f32x4 acc[2][4] = {};
        // x-part MFMAs (h-independent; overlap producer wait)
#pragma unroll
        for (int kt = 0; kt < 2; ++kt)
#pragma unroll
            for (int m = 0; m < 2; ++m)
#pragma unroll
                for (int j = 0; j < 4; ++j)
                    acc[m][j] = __builtin_amdgcn_mfma_f32_16x16x32_f16(ax[m][kt], bw[j][kt], acc[m][j], 0, 0, 0);

        // ---- per-wave producer wait: h_t (parity t&1) flagged with value t ----
        {
            const unsigned want = (unsigned)t;
            while (__hip_atomic_load(cnt + 2 * wid,     __ATOMIC_RELAXED, __HIP_MEMORY_SCOPE_AGENT) < want ||
                   __hip_atomic_load(cnt + 2 * wid + 1, __ATOMIC_RELAXED, __HIP_MEMORY_SCOPE_AGENT) < want)
                __builtin_amdgcn_s_sleep(1);
            __builtin_amdgcn_sched_barrier(0);   // pin h loads below the poll
        }

        // h-part: agent-scope atomic loads (cross-XCD safe), then MFMA
#pragma unroll
        for (int kt = 0; kt < 4; ++kt) {
            U16x8 a0, a1;
            const f16* p0 = hprev + (size_t)(r0 + lrow) * NH + kh0 + kt * 32 + lq * 8;
            const f16* p1 = p0 + (size_t)16 * NH;
            a0.q[0] = __hip_atomic_load((const unsigned long long*)p0, __ATOMIC_RELAXED, __HIP_MEMORY_SCOPE_AGENT);
            a0.q[1] = __hip_atomic_load((const unsigned long long*)p0 + 1, __ATOMIC_RELAXED, __HIP_MEMORY_SCOPE_AGENT);
            a1.q[0] = __hip_atomic_load((const unsigned long long*)p1, __ATOMIC_RELAXED, __HIP_MEMORY_SCOPE_AGENT);
            a1.q[1] = __hip_atomic_load((const unsigned long long*)p1 + 1, __ATOMIC_RELAXED, __HIP_MEMORY_SCOPE_AGENT);
#pragma unroll
            for (int j = 0; j < 4; ++j) {
                acc[0][j] = __builtin_amdgcn_mfma_f32_16x16x32_f16(a0.v, bw[j][2 + kt], acc[0][j], 0, 0, 0);
                acc[1][j] = __builtin_amdgcn_mfma_f32_16x16x32_f16(a1.v, bw[j][2 + kt], acc[1][j], 0, 0, 0);
            }
        }

        // ---- prefetch x for t+1 (latency hides under reduction) ----
        const int tn = (t + 1 < NTT) ? t + 1 : NTT - 1;
#pragma unroll
        for (int m = 0; m < 2; ++m) {
            const float* xp = x + (size_t)(r0 + m * 16 + lrow) * (NTT * ND)
                                + (size_t)tn * ND + kx0 + lq * 8;
#pragma unroll
            for (int kt = 0; kt < 2; ++kt) {
                xf[m][kt][0] = *(const float4*)(xp + kt * 32);
                xf[m][kt][1] = *(const float4*)(xp + kt * 32 + 4);
            }
        }

        // ---- split-K reduction: 8 -> 4 (regs) -> flat 4-buf sum ----
#define ST_PARTIAL(B)                                                          \
        {                                                                      \
            _Pragma("unroll")                                                  \
            for (int m = 0; m < 2; ++m)                                        \
                _Pragma("unroll")                                              \
                for (int j = 0; j < 4; ++j)                                    \
                    *(f32x4*)&red[B][j * 16 + lrow][m * 16 + lq * 4] = acc[m][j]; \
        }
#define ADD_PARTIAL(B)                                                         \
        {                                                                      \
            _Pragma("unroll")                                                  \
            for (int m = 0; m < 2; ++m)                                        \
                _Pragma("unroll")                                              \
                for (int j = 0; j < 4; ++j)                                    \
                    acc[m][j] += *(const f32x4*)&red[B][j * 16 + lrow][m * 16 + lq * 4]; \
        }
        if (wid >= 4) ST_PARTIAL(wid - 4);
        __syncthreads();
        if (wid < 4) {
            ADD_PARTIAL(wid);      // acc = own + partner partial (2-way sums)
            ST_PARTIAL(wid);       // same-wave RAW on own buf: program-order safe
        }
        __syncthreads();

        // ---- epilogue: ALL 8 waves. wave -> 8 cols x 32 rows ----
        {
            f32x4 s = *(const f32x4*)&red[0][ec][eq * 4];
#pragma unroll
            for (int b = 1; b < 4; ++b)
                s += *(const f32x4*)&red[b][ec][eq * 4];
#pragma unroll
            for (int r = 0; r < 4; ++r)
                trans[eq * 4 + r][ec] = (f16)fast_tanh(s[r] + bias_e);
        }
        __syncthreads();

        // ---- store h_new: 512 threads x 8B, coalesced (full 64B lines) ----
        {
            U16x4 u;
            u.v = *(const f16x4*)&trans[srow][sseg * 4];
            __hip_atomic_store((unsigned long long*)(hnew + (size_t)(r0 + srow) * NH + c0 + sseg * 4),
                               u.q, __ATOMIC_RELAXED, __HIP_MEMORY_SCOPE_AGENT);
        }

        // ---- arrival: drain own stores (vmcnt0 at barrier), publish flag ----
        __syncthreads();
        if (tid == 0)
            __hip_atomic_store(cnt + mem, (unsigned)(t + 1), __ATOMIC_RELAXED, __HIP_MEMORY_SCOPE_AGENT);
    }

    // ---- dense head: cluster leader computes out[r0..r0+32) ----
    if (mem == 0) {
        // h_NTT ready = all 16 producers' flags == NTT (per-wave polls only
        // covered flags >= NTT-1 during the last iteration).
        if (tid < 16) {
            while (__hip_atomic_load(cnt + tid, __ATOMIC_RELAXED, __HIP_MEMORY_SCOPE_AGENT) < (unsigned)NTT)
                __builtin_amdgcn_s_sleep(1);
        }
        __syncthreads();
        __builtin_amdgcn_sched_barrier(0);   // pin head loads below the wait

        const f16* hlast = h;                   // parity 0 (NTT even)
        const int r = tid >> 4, seg = tid & 15; // 32 rows x 16 segments of 64
        const f16* hp = hlast + (size_t)(r0 + r) * NH + seg * 64;
        const float* wp = Wd + seg * 64;
        float s = 0.f;
#pragma unroll
        for (int i = 0; i < 64; i += 8) {
            U16x8 u;
            u.q[0] = __hip_atomic_load((const unsigned long long*)(hp + i), __ATOMIC_RELAXED, __HIP_MEMORY_SCOPE_AGENT);
            u.q[1] = __hip_atomic_load((const unsigned long long*)(hp + i) + 1, __ATOMIC_RELAXED, __HIP_MEMORY_SCOPE_AGENT);
            const float4 w0 = *(const float4*)(wp + i);
            const float4 w1 = *(const float4*)(wp + i + 4);
            s += (float)u.v[0] * w0.x + (float)u.v[1] * w0.y +
                 (float)u.v[2] * w0.z + (float)u.v[3] * w0.w +
                 (float)u.v[4] * w1.x + (float)u.v[5] * w1.y +
                 (float)u.v[6] * w1.z + (float)u.v[7] * w1.w;
        }
        s += __shfl_xor(s, 1); s += __shfl_xor(s, 2);
        s += __shfl_xor(s, 4); s += __shfl_xor(s, 8);
        if (seg == 0) out[r0 + r] = s + bd[0];
    }
}

// ---------------------------------------------------------------------------
extern "C" void kernel_launch(void* const* d_in, const int* in_sizes, int n_in,
                              void* d_out, int out_size, void* d_ws, size_t ws_size,
                              hipStream_t stream) {
    const float* x  = (const float*)d_in[0];
    const float* W  = (const float*)d_in[1];
    const float* U  = (const float*)d_in[2];
    const float* b  = (const float*)d_in[3];
    const float* Wd = (const float*)d_in[4];
    const float* bd = (const float*)d_in[5];
    float* out = (float*)d_out;

    char* ws = (char*)d_ws;
    unsigned* bar = (unsigned*)ws;
    f16* WUT = (f16*)(ws + WUT_OFF);
    f16* h   = (f16*)(ws + H_OFF);

    hipMemsetAsync(bar, 0, BAR_BYTES, stream);
    hipMemsetAsync(h, 0, NB * NH * 2, stream);   // h_0 = 0 (parity 0)
    prep_wut<<<dim3(384), dim3(256), 0, stream>>>(W, U, WUT);

    void* args[8] = {(void*)&x, (void*)&WUT, (void*)&b, (void*)&Wd,
                     (void*)&bd, (void*)&h, (void*)&bar, (void*)&out};
    hipError_t err = hipLaunchCooperativeKernel(
        reinterpret_cast<const void*>(&rnn4), dim3(256), dim3(512), args, 0, stream);
    if (err != hipSuccess) {
        // Plain-launch fallback: 256 blocks of 8 waves fit 1/CU on 256 CUs;
        // sync is our own cluster-local atomic barrier, not cg.
        rnn4<<<dim3(256), dim3(512), 0, stream>>>(x, WUT, b, Wd, bd, h, bar, out);
    }
}